// Round 15
// baseline (49.262 us; speedup 1.0000x reference)
//
#include <hip/hip_runtime.h>

// SSIM loss, 7x7 window, VALID, (64,1,512,512) fp32.
// R15: NO LDS in main loop. Each lane loads its own 7 taps directly from
// global via two overlapping float4 loads per array (xa=taps0-3 at col c,
// xb=taps3-6 at col c+3; dword-aligned is legal on gfx950, lanes coalesce
// in L1). Removes the DS pipe (~24-36us/CU serial cost in R12/R14) and all
// halo logic. 4 vertical channels (ss=sxx+syy folded). Depth-1 prefetch.

constexpr int B  = 64;
constexpr int H  = 512, W = 512;
constexpr int OH = H - 6, OW = W - 6;     // 506
constexpr int CW = 64;                    // cols per wave
constexpr int BW_ = 4 * CW;               // cols per block
constexpr int SH = 32;                    // output rows per block

typedef float f4 __attribute__((ext_vector_type(4), aligned(4)));

__global__ __launch_bounds__(256)
void ssim_main(const float* __restrict__ X, const float* __restrict__ Y,
               const float* __restrict__ DR, float* __restrict__ partials)
{
    const int tid  = threadIdx.x;
    const int wid  = tid >> 6;
    const int lane = tid & 63;
    const int c0   = blockIdx.x * BW_ + wid * CW;
    const int r0   = blockIdx.y * SH;
    const int b    = blockIdx.z;

    const int out_rows = min(SH, OH - r0);
    const int rows_in  = out_rows + 6;       // <= 38, block-uniform

    const float d  = DR[b];
    const float C1 = (0.01f * d) * (0.01f * d);
    const float C2 = (0.03f * d) * (0.03f * d);
    const float c1s = 2401.0f * C1;          // 49^2 * C1
    const float c2s = 2352.0f * C2;          // 48*49 * C2

    const int c = c0 + lane;
    const bool colvalid = c < OW;
    const int cc = colvalid ? c : (OW - 1);  // clamp: loads reach <= col 511

    const float* px = X + (size_t)b * H * W + (size_t)r0 * W + cc;
    const float* py = Y + (size_t)b * H * W + (size_t)r0 * W + cc;

    // vertical state: 4 channels, 7-row history
    float bhx[7], bhy[7], bhxy[7], bhss[7];
    float vx = 0.f, vy = 0.f, vxy = 0.f, vss = 0.f;
#pragma unroll
    for (int i = 0; i < 7; ++i) { bhx[i]=bhy[i]=bhxy[i]=bhss[i]=0.f; }

    float acc = 0.f;

    // depth-1 prefetch registers
    f4 pxa = *(const f4*)px;       f4 pxb = *(const f4*)(px + 3);
    f4 pya = *(const f4*)py;       f4 pyb = *(const f4*)(py + 3);
    px += W; py += W;

    for (int rr = 0; rr < 42; rr += 14) {
#pragma unroll
        for (int p = 0; p < 14; ++p) {
            const int r = rr + p;            // r%7 == p%7
            if (r < rows_in) {               // block-uniform
                const f4 xa = pxa, xb = pxb, ya = pya, yb = pyb;

                // issue next row's loads; latency hides under compute + TLP
                if (r + 1 < rows_in) {
                    pxa = *(const f4*)px;  pxb = *(const f4*)(px + 3);
                    pya = *(const f4*)py;  pyb = *(const f4*)(py + 3);
                    px += W; py += W;
                }

                // taps: xa = t0..t3, xb.yzw = t4..t6 (xb.x duplicates t3)
                const float hx = ((xa.x+xa.y)+(xa.z+xa.w)) + ((xb.y+xb.z)+xb.w);
                const float hy = ((ya.x+ya.y)+(ya.z+ya.w)) + ((yb.y+yb.z)+yb.w);
                float hxy = xa.x*ya.x;
                hxy = fmaf(xa.y,ya.y,hxy); hxy = fmaf(xa.z,ya.z,hxy);
                hxy = fmaf(xa.w,ya.w,hxy); hxy = fmaf(xb.y,yb.y,hxy);
                hxy = fmaf(xb.z,yb.z,hxy); hxy = fmaf(xb.w,yb.w,hxy);
                float hss = xa.x*xa.x;
                hss = fmaf(xa.y,xa.y,hss); hss = fmaf(xa.z,xa.z,hss);
                hss = fmaf(xa.w,xa.w,hss); hss = fmaf(xb.y,xb.y,hss);
                hss = fmaf(xb.z,xb.z,hss); hss = fmaf(xb.w,xb.w,hss);
                hss = fmaf(ya.x,ya.x,hss); hss = fmaf(ya.y,ya.y,hss);
                hss = fmaf(ya.z,ya.z,hss); hss = fmaf(ya.w,ya.w,hss);
                hss = fmaf(yb.y,yb.y,hss); hss = fmaf(yb.z,yb.z,hss);
                hss = fmaf(yb.w,yb.w,hss);

                // vertical running 7-row window (slot p%7 holds row r-7)
                constexpr int s7[14] = {0,1,2,3,4,5,6,0,1,2,3,4,5,6};
                const int sp = s7[p];
                vx  += hx  - bhx[sp];  bhx[sp]  = hx;
                vy  += hy  - bhy[sp];  bhy[sp]  = hy;
                vxy += hxy - bhxy[sp]; bhxy[sp] = hxy;
                vss += hss - bhss[sp]; bhss[sp] = hss;

                if (r >= 6 && colvalid) {
                    // S = (2 sx sy + c1s)(2(49 sxy - sx sy) + c2s)
                    //   / (sx^2+sy^2+c1s)(49 ss - sx^2 - sy^2 + c2s)
                    const float p1 = vx * vy;
                    const float t1 = fmaf(2.f, p1, c1s);
                    const float q  = fmaf(49.f, vxy, -p1);
                    const float t2 = fmaf(2.f, q, c2s);
                    const float n2 = fmaf(vy, vy, vx * vx);
                    const float b1 = n2 + c1s;
                    const float b2 = fmaf(49.f, vss, c2s) - n2;
                    const float den = b1 * b2;
                    float rc = __builtin_amdgcn_rcpf(den);
                    rc = rc * (2.f - den * rc);          // 1 Newton step
                    acc = fmaf(t1 * t2, rc, acc);
                }
            }
        }
    }

    // block reduction: wave shfl, then cross-wave via LDS (single barrier)
    float s = acc;
#pragma unroll
    for (int o = 32; o; o >>= 1) s += __shfl_down(s, o, 64);
    __shared__ float wsum[4];
    if (lane == 0) wsum[wid] = s;
    __syncthreads();
    if (tid == 0) {
        const int bid = (blockIdx.z * gridDim.y + blockIdx.y) * gridDim.x + blockIdx.x;
        partials[bid] = wsum[0] + wsum[1] + wsum[2] + wsum[3];
    }
}

__global__ __launch_bounds__(256)
void ssim_final(const float* __restrict__ partials, int n,
                float* __restrict__ out, float inv_count)
{
    const int tid = threadIdx.x;
    float s = 0.f;
    for (int i = tid; i < n; i += 256) s += partials[i];
#pragma unroll
    for (int o = 32; o; o >>= 1) s += __shfl_down(s, o, 64);
    __shared__ float wsum[4];
    if ((tid & 63) == 0) wsum[tid >> 6] = s;
    __syncthreads();
    if (tid == 0) out[0] = 1.0f - (wsum[0] + wsum[1] + wsum[2] + wsum[3]) * inv_count;
}

extern "C" void kernel_launch(void* const* d_in, const int* in_sizes, int n_in,
                              void* d_out, int out_size, void* d_ws, size_t ws_size,
                              hipStream_t stream)
{
    const float* X  = (const float*)d_in[0];
    const float* Y  = (const float*)d_in[1];
    const float* DR = (const float*)d_in[2];
    float* out      = (float*)d_out;
    float* partials = (float*)d_ws;

    const int gx = (OW + BW_ - 1) / BW_; // 2
    const int gy = (OH + SH - 1) / SH;   // 16
    dim3 grid(gx, gy, B);                // 2048 blocks, every partial slot written
    ssim_main<<<grid, 256, 0, stream>>>(X, Y, DR, partials);

    const int n = gx * gy * B;           // 2048
    const float inv_count = 1.0f / (float)((long)B * OH * OW);
    ssim_final<<<1, 256, 0, stream>>>(partials, n, out, inv_count);
}